// Round 5
// baseline (290.741 us; speedup 1.0000x reference)
//
#include <hip/hip_runtime.h>
#include <math.h>
#include <stdint.h>

#define H 512
#define W 512
#define NPIX (H * W)          // 262144
#define NB 2
#define NF 180
#define KS 17
#define WSCALE 1024.0f        // exact power of two; cancels in both outputs

typedef _Float16 half8 __attribute__((ext_vector_type(8)));
typedef float floatx16 __attribute__((ext_vector_type(16)));
typedef uint32_t u32x4 __attribute__((ext_vector_type(4)));

union FragU { u32x4 u; half8 h; };

// ---------------- taps (match numpy float64 _gauss1d) ----------------
__global__ void k_taps(float* __restrict__ taps) {
  if (threadIdx.x == 0 && blockIdx.x == 0) {
    {
      double k[5], s = 0.0;
      for (int i = 0; i < 5; i++) { double xv = (double)(i - 2) / 0.4; k[i] = exp(-0.5 * xv * xv); s += k[i]; }
      for (int i = 0; i < 5; i++) taps[i] = (float)(k[i] / s);
    }
    {
      double k[81], s = 0.0;
      for (int i = 0; i < 81; i++) { double xv = (double)(i - 40) / 10.0; k[i] = exp(-0.5 * xv * xv); s += k[i]; }
      for (int i = 0; i < 81; i++) taps[8 + i] = (float)(k[i] / s);
    }
  }
}

// ---------------- weight repack into MFMA B-fragment order, f16 split ----------------
// Bf layout (u32): chunk c (19): [c*3072 .. ]: h-frags: t*256 + lane*4 + q ; l-frags at +1536
// B[k][n]: lane: n = t*32 + (lane&31), k = 8*(lane>>5) + j, dword q holds j=2q (lo16), j=2q+1 (hi16)
// chunks: c<17: (ky=c, kx=k); c==17: (ky=k, kx=16); c==18: k==0 -> (ky=16,kx=16)
__global__ void k_repackB(const float* __restrict__ w, uint32_t* __restrict__ Bf) {
  int tid = blockIdx.x * 256 + threadIdx.x;
  if (tid >= 19 * 6 * 64 * 4) return;
  int q = tid & 3;
  int lane = (tid >> 2) & 63;
  int ct = tid >> 8;
  int t = ct % 6, c = ct / 6;
  int n = t * 32 + (lane & 31);
  int hf = lane >> 5;
  uint32_t hv = 0, lv = 0;
  for (int s = 0; s < 2; s++) {
    int j = 2 * q + s;
    int k = hf * 8 + j;   // 0..15
    float val = 0.f;
    if (n < NF) {
      if (c < 17)       val = w[n * 289 + c * 17 + k];
      else if (c == 17) val = w[n * 289 + k * 17 + 16];
      else if (k == 0)  val = w[n * 289 + 16 * 17 + 16];
    }
    val *= WSCALE;
    _Float16 hh = (_Float16)val;
    _Float16 ll = (_Float16)(val - (float)hh);
    hv |= (uint32_t)__builtin_bit_cast(uint16_t, hh) << (16 * s);
    lv |= (uint32_t)__builtin_bit_cast(uint16_t, ll) << (16 * s);
  }
  int base = c * 3072;
  int off = t * 256 + lane * 4 + q;
  Bf[base + off] = hv;
  Bf[base + 1536 + off] = lv;
}

// ---------------- gray ----------------
__global__ void k_gray(const float* __restrict__ x, float* __restrict__ gray) {
  int i = blockIdx.x * blockDim.x + threadIdx.x;
  if (i >= NB * NPIX) return;
  int b = i / NPIX, r = i % NPIX;
  const float* xb = x + (size_t)b * 3 * NPIX;
  gray[i] = 0.2989f * xb[r] + 0.587f * xb[NPIX + r] + 0.114f * xb[2 * NPIX + r];
}

// ---------------- vertical blur, both sigmas fused ----------------
__global__ void k_vblur2(const float* __restrict__ in, float* __restrict__ outA,
                         float* __restrict__ outB, const float* __restrict__ taps) {
  int i = blockIdx.x * blockDim.x + threadIdx.x;
  if (i >= NB * NPIX) return;
  int b = i / NPIX, r = i % NPIX;
  int y = r / W, xx = r % W;
  const float* img = in + (size_t)b * NPIX;
  float a = 0.f;
#pragma unroll
  for (int j = -2; j <= 2; j++) {
    int yy = y + j; yy = yy < 0 ? 0 : (yy > H - 1 ? H - 1 : yy);
    a = fmaf(taps[j + 2], img[yy * W + xx], a);
  }
  float c = 0.f;
  for (int j = -40; j <= 40; j++) {
    int yy = y + j; yy = yy < 0 ? 0 : (yy > H - 1 ? H - 1 : yy);
    c = fmaf(taps[8 + j + 40], img[yy * W + xx], c);
  }
  outA[i] = a;
  outB[i] = c;
}

// ---------------- horizontal blur + DoG + f16-split pack ----------------
__global__ void k_hblur_dog(const float* __restrict__ inA, const float* __restrict__ inB,
                            uint32_t* __restrict__ dogp, const float* __restrict__ taps) {
  int i = blockIdx.x * blockDim.x + threadIdx.x;
  if (i >= NB * NPIX) return;
  int b = i / NPIX, r = i % NPIX;
  int y = r / W, xx = r % W;
  const float* ra = inA + (size_t)b * NPIX + (size_t)y * W;
  const float* rb = inB + (size_t)b * NPIX + (size_t)y * W;
  float a = 0.f;
#pragma unroll
  for (int j = -2; j <= 2; j++) {
    int xc = xx + j; xc = xc < 0 ? 0 : (xc > W - 1 ? W - 1 : xc);
    a = fmaf(taps[j + 2], ra[xc], a);
  }
  float c = 0.f;
  for (int j = -40; j <= 40; j++) {
    int xc = xx + j; xc = xc < 0 ? 0 : (xc > W - 1 ? W - 1 : xc);
    c = fmaf(taps[8 + j + 40], rb[xc], c);
  }
  float d = a - c;
  _Float16 hh = (_Float16)d;
  _Float16 ll = (_Float16)(d - (float)hh);
  dogp[i] = ((uint32_t)__builtin_bit_cast(uint16_t, ll) << 16) |
            (uint32_t)__builtin_bit_cast(uint16_t, hh);
}

// ---------------- main: implicit-GEMM MFMA conv, barrier-free main loop ----------------
// block: 256 thr = 4 waves; wave w = r*2+g: r = row (0..1), g = n-group (0..1)
// wave tile: M=64 px (2 m-tiles of 32), N=96 (3 n-tiles); B read from global (L1-hot),
// register double-buffered; acc = 96 VGPR -> 2 waves/SIMD.
__launch_bounds__(256, 2)
__global__ void k_conv(const uint32_t* __restrict__ dogp,
                       const uint32_t* __restrict__ Bf,
                       const float* __restrict__ bins,
                       float* __restrict__ out) {
  __shared__ uint32_t stile[19 * 80];   // packed (hi|lo f16) input rows
  __shared__ float pm[2][2][64];
  __shared__ int   pn[2][2][64];
  __shared__ float pS[2][2][64];
  __shared__ float pc[2][2][64];
  __shared__ int   fn[2][64];
  __shared__ float fS[2][64];

  const int b  = blockIdx.z;
  const int y0 = blockIdx.y * 2;
  const int x0 = blockIdx.x * 64;
  const int tid = threadIdx.x;
  const int lane = tid & 63;
  const int w  = __builtin_amdgcn_readfirstlane(tid >> 6);  // 0..3
  const int r  = w >> 1;        // row within block
  const int g  = w & 1;         // n-group (filters g*96 .. g*96+95)
  const int nl = lane & 31;
  const int half = lane >> 5;

  // stage input tile rows y0-8 .. y0+10, x0-8 .. x0+71 (zero-padded)
  const uint32_t* dgb = dogp + (size_t)b * NPIX;
  for (int i = tid; i < 19 * 80; i += 256) {
    int ry = i / 80, rx = i % 80;
    int gy = y0 + ry - 8, gx = x0 + rx - 8;
    uint32_t v = 0;
    if (gy >= 0 && gy < H && gx >= 0 && gx < W) v = dgb[gy * W + gx];
    stile[i] = v;
  }
  __syncthreads();

  floatx16 acc[2][3];
#pragma unroll
  for (int mt = 0; mt < 2; mt++)
#pragma unroll
    for (int t = 0; t < 3; t++)
#pragma unroll
      for (int q = 0; q < 16; q++) acc[mt][t][q] = 0.f;

  // B base for this wave's n-group; per chunk: 3 hi frags + 3 lo frags (dwordx4/lane)
  const uint32_t* Bbase = Bf + (size_t)g * 768 + (size_t)lane * 4;

  FragU bh[3], bl[3], nh[3], nlo[3];
#pragma unroll
  for (int t = 0; t < 3; t++) {
    bh[t].u = *(const u32x4*)(Bbase + t * 256);
    bl[t].u = *(const u32x4*)(Bbase + 1536 + t * 256);
  }

  for (int c = 0; c < 19; c++) {
    // prefetch next chunk's B frags into regs (no barrier anywhere in this loop)
    if (c + 1 < 19) {
      const uint32_t* src = Bbase + (size_t)(c + 1) * 3072;
#pragma unroll
      for (int t = 0; t < 3; t++) {
        nh[t].u = *(const u32x4*)(src + t * 256);
        nlo[t].u = *(const u32x4*)(src + 1536 + t * 256);
      }
    }

    // build A fragments (hi & lo) for both m-tiles
    uint32_t ah[2][4], al[2][4];
    if (c < 17) {
#pragma unroll
      for (int mt = 0; mt < 2; mt++) {
        const uint32_t* rp = &stile[(r + c) * 80 + mt * 32 + nl + half * 8];
        uint32_t d[8];
#pragma unroll
        for (int j = 0; j < 8; j++) d[j] = rp[j];
#pragma unroll
        for (int q = 0; q < 4; q++) {
          ah[mt][q] = __builtin_amdgcn_perm(d[2 * q + 1], d[2 * q], 0x05040100u);
          al[mt][q] = __builtin_amdgcn_perm(d[2 * q + 1], d[2 * q], 0x07060302u);
        }
      }
    } else {
      int kyb = (c - 17) * 16 + half * 8;
#pragma unroll
      for (int mt = 0; mt < 2; mt++) {
        uint32_t d[8];
#pragma unroll
        for (int j = 0; j < 8; j++) {
          int ky = kyb + j; if (ky > 16) ky = 16;   // clamped reads are killed by B=0
          d[j] = stile[(r + ky) * 80 + mt * 32 + nl + 16];
        }
#pragma unroll
        for (int q = 0; q < 4; q++) {
          ah[mt][q] = __builtin_amdgcn_perm(d[2 * q + 1], d[2 * q], 0x05040100u);
          al[mt][q] = __builtin_amdgcn_perm(d[2 * q + 1], d[2 * q], 0x07060302u);
        }
      }
    }

    // MFMA: 3 n-tiles x 2 m-tiles x 3-term split
#pragma unroll
    for (int t = 0; t < 3; t++) {
#pragma unroll
      for (int mt = 0; mt < 2; mt++) {
        FragU fh, fl;
        fh.u.x = ah[mt][0]; fh.u.y = ah[mt][1]; fh.u.z = ah[mt][2]; fh.u.w = ah[mt][3];
        fl.u.x = al[mt][0]; fl.u.y = al[mt][1]; fl.u.z = al[mt][2]; fl.u.w = al[mt][3];
        acc[mt][t] = __builtin_amdgcn_mfma_f32_32x32x16_f16(fh.h, bh[t].h, acc[mt][t], 0, 0, 0);
        acc[mt][t] = __builtin_amdgcn_mfma_f32_32x32x16_f16(fl.h, bh[t].h, acc[mt][t], 0, 0, 0);
        acc[mt][t] = __builtin_amdgcn_mfma_f32_32x32x16_f16(fh.h, bl[t].h, acc[mt][t], 0, 0, 0);
      }
    }

#pragma unroll
    for (int t = 0; t < 3; t++) { bh[t] = nh[t]; bl[t] = nlo[t]; }
  }

  // ---- epilogue ----
  const float PI_F = 3.14159265358979323846f;

  // stage 1: per-wave partial argmax/sum over its 96 filters, per output pixel
#pragma unroll
  for (int mt = 0; mt < 2; mt++) {
#pragma unroll
    for (int q = 0; q < 16; q++) {
      float m = -1.f, S = 0.f;
      int bt = 0;
#pragma unroll
      for (int t = 0; t < 3; t++) {
        float v = fabsf(acc[mt][t][q]);
        S += v;
        if (v > m) { m = v; bt = t; }
      }
      int n = g * 96 + bt * 32 + nl;
#pragma unroll
      for (int msk = 1; msk < 32; msk <<= 1) {
        float vo = __shfl_xor(m, msk);
        int   no = __shfl_xor(n, msk);
        float So = __shfl_xor(S, msk);
        bool take = (vo > m) || (vo == m && no < n);
        m = take ? vo : m;
        n = take ? no : n;
        S += So;
      }
      if (nl == 0) {
        int px = mt * 32 + (q & 3) + 8 * (q >> 2) + 4 * half;
        pm[r][g][px] = m; pn[r][g][px] = n; pS[r][g][px] = S;
      }
    }
  }
  __syncthreads();

  // stage 2: g==0 waves combine the two n-groups, write orientation
  if (g == 0) {
    int p = lane;
    float m0 = pm[r][0][p], m1 = pm[r][1][p];
    int n = (m1 > m0) ? pn[r][1][p] : pn[r][0][p];   // strict > keeps smaller index on tie
    float S = pS[r][0][p] + pS[r][1][p];
    fn[r][p] = n; fS[r][p] = S;
    float om = (float)n / 180.0f * 255.0f;
    out[(size_t)b * NPIX + (size_t)(y0 + r) * W + x0 + p] = om;
  }
  __syncthreads();

  // stage 3: per-wave partial confidence with the final winner
  {
    float bn[3];
#pragma unroll
    for (int t = 0; t < 3; t++) {
      int n = g * 96 + t * 32 + nl;
      bn[t] = (n < NF) ? bins[n] : 0.f;
    }
#pragma unroll
    for (int mt = 0; mt < 2; mt++) {
#pragma unroll
      for (int q = 0; q < 16; q++) {
        int px = mt * 32 + (q & 3) + 8 * (q >> 2) + 4 * half;
        int nwin = fn[r][px];
        float om = (float)nwin / 180.0f * 255.0f;
        float rad = om / 180.0f * PI_F;
        float C = 0.f;
#pragma unroll
        for (int t = 0; t < 3; t++) {
          float dd = rad - bn[t];
          float d0 = fabsf(dd);
          float d1 = fabsf(dd - PI_F);
          float d2 = fabsf(dd + PI_F);
          float d = fminf(d0, fminf(d1, d2));
          C = fmaf(d * d, fabsf(acc[mt][t][q]), C);
        }
#pragma unroll
        for (int msk = 1; msk < 32; msk <<= 1) C += __shfl_xor(C, msk);
        if (nl == 0) pc[r][g][px] = C;
      }
    }
  }
  __syncthreads();

  // stage 4: g==0 waves finalize confidence
  if (g == 0) {
    int p = lane;
    float C = pc[r][0][p] + pc[r][1][p];
    out[(size_t)NB * NPIX + (size_t)b * NPIX + (size_t)(y0 + r) * W + x0 + p] = C / fS[r][p];
  }
}

extern "C" void kernel_launch(void* const* d_in, const int* in_sizes, int n_in,
                              void* d_out, int out_size, void* d_ws, size_t ws_size,
                              hipStream_t stream) {
  const float* x = (const float*)d_in[0];      // [2,3,512,512]
  const float* wts = (const float*)d_in[1];    // [180,1,17,17]
  const float* bins = (const float*)d_in[2];   // [180]
  float* out = (float*)d_out;

  float* ws = (float*)d_ws;
  float* gray = ws;                                 // 524288 f32
  float* tmpA = ws + (size_t)NB * NPIX;             // 524288 f32
  float* tmpB = tmpA + (size_t)NB * NPIX;           // 524288 f32
  uint32_t* dogp = (uint32_t*)(tmpB + (size_t)NB * NPIX);  // 524288 u32
  float* taps = (float*)(dogp + (size_t)NB * NPIX); // 128 f32
  uint32_t* Bf = (uint32_t*)(taps + 128);           // 19*3072 u32

  k_taps<<<1, 64, 0, stream>>>(taps);
  k_repackB<<<114, 256, 0, stream>>>(wts, Bf);

  int n = NB * NPIX;
  int blk = 256, grd = (n + blk - 1) / blk;
  k_gray<<<grd, blk, 0, stream>>>(x, gray);
  k_vblur2<<<grd, blk, 0, stream>>>(gray, tmpA, tmpB, taps);
  k_hblur_dog<<<grd, blk, 0, stream>>>(tmpA, tmpB, dogp, taps);

  dim3 g(W / 64, H / 2, NB);
  k_conv<<<g, 256, 0, stream>>>(dogp, Bf, bins, out);
}